// Round 1
// baseline (184.282 us; speedup 1.0000x reference)
//
#include <hip/hip_runtime.h>

#define N 1024
#define F 32
#define H 64
#define NEATTR 8

// Kernel 1: self_term[v,h] = b[h] + sum_f X[v,f]*(W[f,h]-W[32+f,h])
//           nbr_term[v,h]  =        sum_f X[v,f]*W[32+f,h]
__global__ __launch_bounds__(256) void precompute_terms(
    const float* __restrict__ X,   // N x F
    const float* __restrict__ W,   // 72 x 64 row-major
    const float* __restrict__ b,   // 64
    float* __restrict__ sv,        // N x H (self + bias)
    float* __restrict__ nb)        // N x H
{
    int idx = blockIdx.x * blockDim.x + threadIdx.x; // 0..65535
    int v = idx >> 6;
    int h = idx & 63;
    float s = b[h];
    float n = 0.f;
#pragma unroll
    for (int f = 0; f < F; ++f) {
        float x  = X[v * F + f];
        float ws = W[f * H + h];
        float wd = W[(F + f) * H + h];
        s = fmaf(x, ws - wd, s);
        n = fmaf(x, wd, n);
    }
    sv[idx] = s;
    nb[idx] = n;
}

// Kernel 2: one block per node v; lane = output channel h; 4 waves split w.
__global__ __launch_bounds__(256) void edge_aggregate(
    const int* __restrict__ A,      // N x N (0/1)
    const float* __restrict__ Edge, // N x N x 8
    const float* __restrict__ W,    // 72 x 64
    const float* __restrict__ sv,   // N x H  (self + b)
    const float* __restrict__ nb,   // N x H
    float* __restrict__ out)        // N x H
{
    const int v    = blockIdx.x;
    const int lane = threadIdx.x & 63;
    const int wid  = threadIdx.x >> 6;

    // W_edge column for this lane: wc[e] = W[(64+e)*64 + lane]
    float wc[NEATTR];
#pragma unroll
    for (int e = 0; e < NEATTR; ++e) wc[e] = W[(2 * F + e) * H + lane];

    const float s = sv[v * H + lane];

    const int* __restrict__ Arow = A + (size_t)v * N;
    const float4* __restrict__ E4 = (const float4*)(Edge + (size_t)v * N * NEATTR);

    float acc = 0.f;
    const int w0 = wid * (N / 4);
    const int w1 = w0 + (N / 4);
    for (int w = w0; w < w1; ++w) {
        // A[v,w] is identical across the 64 lanes -> wave-uniform branch
        if (Arow[w] != 0) {
            float t = s + nb[w * H + lane];          // coalesced 256B load
            float4 ea = E4[w * 2];                   // broadcast 16B
            float4 eb = E4[w * 2 + 1];               // broadcast 16B
            t = fmaf(ea.x, wc[0], t);
            t = fmaf(ea.y, wc[1], t);
            t = fmaf(ea.z, wc[2], t);
            t = fmaf(ea.w, wc[3], t);
            t = fmaf(eb.x, wc[4], t);
            t = fmaf(eb.y, wc[5], t);
            t = fmaf(eb.z, wc[6], t);
            t = fmaf(eb.w, wc[7], t);
            acc += fmaxf(t, 0.f);
        }
    }

    __shared__ float part[4][64];
    part[wid][lane] = acc;
    __syncthreads();
    if (threadIdx.x < 64) {
        out[v * H + lane] =
            part[0][lane] + part[1][lane] + part[2][lane] + part[3][lane];
    }
}

extern "C" void kernel_launch(void* const* d_in, const int* in_sizes, int n_in,
                              void* d_out, int out_size, void* d_ws, size_t ws_size,
                              hipStream_t stream) {
    const int*   A    = (const int*)d_in[0];    // adjacency (1,1024,1024) int32
    const float* X    = (const float*)d_in[1];  // node_features (1,1024,32)
    const float* Edge = (const float*)d_in[2];  // edge_attributes (1,1024,1024,8)
    const float* W    = (const float*)d_in[3];  // (72,64)
    const float* b    = (const float*)d_in[4];  // (64,)
    float* out = (float*)d_out;                 // (1,1024,64)

    float* sv = (float*)d_ws;                   // N*H floats
    float* nb = sv + N * H;                     // N*H floats

    precompute_terms<<<dim3(256), dim3(256), 0, stream>>>(X, W, b, sv, nb);
    edge_aggregate<<<dim3(N), dim3(256), 0, stream>>>(A, Edge, W, sv, nb, out);
}

// Round 2
// 142.692 us; speedup vs baseline: 1.2915x; 1.2915x over previous
//
#include <hip/hip_runtime.h>

#define N 1024
#define F 32
#define H 64
#define NEATTR 8
#define WCHUNK 64
#define NCHUNK (N / WCHUNK)   // 16
// block: 256 threads = 4 waves; each wave owns 2 v-rows; block owns 8 v-rows.
// grid = (N/8) v-groups * NCHUNK w-chunks = 128 * 16 = 2048 blocks -> 8 blocks/CU.

// Kernel 1: self_term[v,h] = b[h] + sum_f X[v,f]*(W[f,h]-W[32+f,h])
//           nbr_term[v,h]  =        sum_f X[v,f]*W[32+f,h]
// Also zeroes out[] (exactly N*H threads) so kernel 2 can atomicAdd.
__global__ __launch_bounds__(256) void precompute_terms(
    const float* __restrict__ X,   // N x F
    const float* __restrict__ W,   // 72 x 64 row-major
    const float* __restrict__ b,   // 64
    float* __restrict__ sv,        // N x H (self + bias)
    float* __restrict__ nb,        // N x H
    float* __restrict__ out)       // N x H (zero-init)
{
    int idx = blockIdx.x * blockDim.x + threadIdx.x; // 0..65535
    int v = idx >> 6;
    int h = idx & 63;
    float s = b[h];
    float n = 0.f;
#pragma unroll
    for (int f = 0; f < F; ++f) {
        float x  = X[v * F + f];
        float ws = W[f * H + h];
        float wd = W[(F + f) * H + h];
        s = fmaf(x, ws - wd, s);
        n = fmaf(x, wd, n);
    }
    sv[idx] = s;
    nb[idx] = n;
    out[idx] = 0.f;
}

// Kernel 2: branchless masked aggregation, wave = 64 lanes = 64 h-channels.
__global__ __launch_bounds__(256) void edge_aggregate(
    const int* __restrict__ A,      // N x N (0/1)
    const float* __restrict__ Edge, // N x N x 8
    const float* __restrict__ W,    // 72 x 64
    const float* __restrict__ sv,   // N x H  (self + b)
    const float* __restrict__ nb,   // N x H
    float* __restrict__ out)        // N x H (atomicAdd target)
{
    const int lane  = threadIdx.x & 63;
    const int wid   = threadIdx.x >> 6;
    const int chunk = blockIdx.x & (NCHUNK - 1);
    const int vgrp  = blockIdx.x >> 4;

    const int v0 = vgrp * 8 + wid * 2;
    const int v1 = v0 + 1;
    const int wbase = chunk * WCHUNK;

    // W_edge column for this lane
    float wc[NEATTR];
#pragma unroll
    for (int e = 0; e < NEATTR; ++e) wc[e] = W[(2 * F + e) * H + lane];

    const float s0 = sv[v0 * H + lane];
    const float s1 = sv[v1 * H + lane];

    // A chunk: one coalesced load per row, then register-shuffle per iteration
    const int a0i = A[(size_t)v0 * N + wbase + lane];
    const int a1i = A[(size_t)v1 * N + wbase + lane];

    const float4* __restrict__ E0 = (const float4*)(Edge + (size_t)v0 * N * NEATTR);
    const float4* __restrict__ E1 = (const float4*)(Edge + (size_t)v1 * N * NEATTR);
    const float* __restrict__ nbp = nb + (size_t)wbase * H + lane;

    float acc0 = 0.f;
    float acc1 = 0.f;

#pragma unroll 2
    for (int j = 0; j < WCHUNK; ++j) {
        const int w = wbase + j;
        const float a0 = (float)__shfl(a0i, j, 64);
        const float a1 = (float)__shfl(a1i, j, 64);
        const float nbv = nbp[j * H];            // coalesced 256B
        float4 ea0 = E0[w * 2];                  // broadcast 16B loads
        float4 eb0 = E0[w * 2 + 1];
        float4 ea1 = E1[w * 2];
        float4 eb1 = E1[w * 2 + 1];

        float t0 = s0 + nbv;
        t0 = fmaf(ea0.x, wc[0], t0);
        t0 = fmaf(ea0.y, wc[1], t0);
        t0 = fmaf(ea0.z, wc[2], t0);
        t0 = fmaf(ea0.w, wc[3], t0);
        t0 = fmaf(eb0.x, wc[4], t0);
        t0 = fmaf(eb0.y, wc[5], t0);
        t0 = fmaf(eb0.z, wc[6], t0);
        t0 = fmaf(eb0.w, wc[7], t0);
        acc0 = fmaf(a0, fmaxf(t0, 0.f), acc0);

        float t1 = s1 + nbv;
        t1 = fmaf(ea1.x, wc[0], t1);
        t1 = fmaf(ea1.y, wc[1], t1);
        t1 = fmaf(ea1.z, wc[2], t1);
        t1 = fmaf(ea1.w, wc[3], t1);
        t1 = fmaf(eb1.x, wc[4], t1);
        t1 = fmaf(eb1.y, wc[5], t1);
        t1 = fmaf(eb1.z, wc[6], t1);
        t1 = fmaf(eb1.w, wc[7], t1);
        acc1 = fmaf(a1, fmaxf(t1, 0.f), acc1);
    }

    unsafeAtomicAdd(&out[v0 * H + lane], acc0);
    unsafeAtomicAdd(&out[v1 * H + lane], acc1);
}

extern "C" void kernel_launch(void* const* d_in, const int* in_sizes, int n_in,
                              void* d_out, int out_size, void* d_ws, size_t ws_size,
                              hipStream_t stream) {
    const int*   A    = (const int*)d_in[0];    // adjacency (1,1024,1024) int32
    const float* X    = (const float*)d_in[1];  // node_features (1,1024,32)
    const float* Edge = (const float*)d_in[2];  // edge_attributes (1,1024,1024,8)
    const float* W    = (const float*)d_in[3];  // (72,64)
    const float* b    = (const float*)d_in[4];  // (64,)
    float* out = (float*)d_out;                 // (1,1024,64)

    float* sv = (float*)d_ws;                   // N*H floats
    float* nb = sv + N * H;                     // N*H floats

    precompute_terms<<<dim3(256), dim3(256), 0, stream>>>(X, W, b, sv, nb, out);
    edge_aggregate<<<dim3((N / 8) * NCHUNK), dim3(256), 0, stream>>>(A, Edge, W, sv, nb, out);
}